// Round 1
// baseline (336.959 us; speedup 1.0000x reference)
//
#include <hip/hip_runtime.h>
#include <math.h>

// afm_27805618274715: gather 3 embeddings/group, pairwise products,
// MLP(64->4 sigmoid ->1) per pair, Linear(3->1), sigmoid*2-1.
// 16 lanes per group (each lane owns 4 of the 64 embed dims),
// 4 groups per wave, 16 groups per 256-thread block.

static constexpr int G_TOTAL = 262144;

__device__ __forceinline__ float sigf(float x) {
    return 1.0f / (1.0f + expf(-x));
}

// partial of (v dot W1[:,f]) for this lane's 4 dims; w0..w3 are W1 rows 4l..4l+3
__device__ __forceinline__ float4 mlp_partial(const float4 v,
                                              const float4 w0, const float4 w1,
                                              const float4 w2, const float4 w3) {
    float4 r;
    r.x = fmaf(v.x, w0.x, fmaf(v.y, w1.x, fmaf(v.z, w2.x, v.w * w3.x)));
    r.y = fmaf(v.x, w0.y, fmaf(v.y, w1.y, fmaf(v.z, w2.y, v.w * w3.y)));
    r.z = fmaf(v.x, w0.z, fmaf(v.y, w1.z, fmaf(v.z, w2.z, v.w * w3.z)));
    r.w = fmaf(v.x, w0.w, fmaf(v.y, w1.w, fmaf(v.z, w2.w, v.w * w3.w)));
    return r;
}

__global__ __launch_bounds__(256) void afm_kernel(
    const int*   __restrict__ group,   // [G,3]
    const float* __restrict__ embed,   // [1M,64]
    const float* __restrict__ W1,      // [64,4] row-major
    const float* __restrict__ b1,      // [4]
    const float* __restrict__ W2,      // [4]
    const float* __restrict__ b2,      // [1]
    const float* __restrict__ Wp,      // [3]
    const float* __restrict__ bp,      // [1]
    float*       __restrict__ out)     // [G]
{
    const int tid  = blockIdx.x * 256 + threadIdx.x;
    const int lane = threadIdx.x & 63;
    const int sub  = lane >> 4;          // subgroup 0..3 within wave
    const int l    = lane & 15;          // lane within subgroup
    const int g    = (tid >> 6) * 4 + sub;

    const int base = g * 3;
    const int i0 = group[base + 0];
    const int i1 = group[base + 1];
    const int i2 = group[base + 2];

    // coalesced: 16 lanes x float4 = one full 256B embedding row
    const float4 e0 = ((const float4*)(embed + (size_t)i0 * 64))[l];
    const float4 e1 = ((const float4*)(embed + (size_t)i1 * 64))[l];
    const float4 e2 = ((const float4*)(embed + (size_t)i2 * 64))[l];

    // W1 rows for this lane's dims 4l..4l+3 (16 floats)
    const float4* w1v = (const float4*)W1 + (l << 2);
    const float4 wr0 = w1v[0];
    const float4 wr1 = w1v[1];
    const float4 wr2 = w1v[2];
    const float4 wr3 = w1v[3];

    // pairwise products (0,1),(0,2),(1,2) fused with W1 partial dot
    float4 v;
    v.x = e0.x * e1.x; v.y = e0.y * e1.y; v.z = e0.z * e1.z; v.w = e0.w * e1.w;
    float4 acc01 = mlp_partial(v, wr0, wr1, wr2, wr3);
    v.x = e0.x * e2.x; v.y = e0.y * e2.y; v.z = e0.z * e2.z; v.w = e0.w * e2.w;
    float4 acc02 = mlp_partial(v, wr0, wr1, wr2, wr3);
    v.x = e1.x * e2.x; v.y = e1.y * e2.y; v.z = e1.z * e2.z; v.w = e1.w * e2.w;
    float4 acc12 = mlp_partial(v, wr0, wr1, wr2, wr3);

    // butterfly reduce across the 16-lane subgroup (xor masks stay in-subgroup)
#pragma unroll
    for (int m = 8; m >= 1; m >>= 1) {
        acc01.x += __shfl_xor(acc01.x, m);
        acc01.y += __shfl_xor(acc01.y, m);
        acc01.z += __shfl_xor(acc01.z, m);
        acc01.w += __shfl_xor(acc01.w, m);
        acc02.x += __shfl_xor(acc02.x, m);
        acc02.y += __shfl_xor(acc02.y, m);
        acc02.z += __shfl_xor(acc02.z, m);
        acc02.w += __shfl_xor(acc02.w, m);
        acc12.x += __shfl_xor(acc12.x, m);
        acc12.y += __shfl_xor(acc12.y, m);
        acc12.z += __shfl_xor(acc12.z, m);
        acc12.w += __shfl_xor(acc12.w, m);
    }

    // tiny epilogue (redundant on all lanes; lane 0 of subgroup stores)
    const float b10 = b1[0], b11 = b1[1], b12 = b1[2], b13 = b1[3];
    const float w20 = W2[0], w21 = W2[1], w22 = W2[2], w23 = W2[3];
    const float b2v = b2[0];

    float a0 = b2v + sigf(acc01.x + b10) * w20 + sigf(acc01.y + b11) * w21
                   + sigf(acc01.z + b12) * w22 + sigf(acc01.w + b13) * w23;
    float a1 = b2v + sigf(acc02.x + b10) * w20 + sigf(acc02.y + b11) * w21
                   + sigf(acc02.z + b12) * w22 + sigf(acc02.w + b13) * w23;
    float a2 = b2v + sigf(acc12.x + b10) * w20 + sigf(acc12.y + b11) * w21
                   + sigf(acc12.z + b12) * w22 + sigf(acc12.w + b13) * w23;

    const float z = bp[0] + a0 * Wp[0] + a1 * Wp[1] + a2 * Wp[2];
    const float res = 2.0f / (1.0f + expf(-z)) - 1.0f;

    if (l == 0) out[g] = res;
}

extern "C" void kernel_launch(void* const* d_in, const int* in_sizes, int n_in,
                              void* d_out, int out_size, void* d_ws, size_t ws_size,
                              hipStream_t stream) {
    const int*   group = (const int*)  d_in[0];
    const float* embed = (const float*)d_in[1];
    const float* W1    = (const float*)d_in[2];
    const float* b1    = (const float*)d_in[3];
    const float* W2    = (const float*)d_in[4];
    const float* b2    = (const float*)d_in[5];
    const float* Wp    = (const float*)d_in[6];
    const float* bp    = (const float*)d_in[7];
    float* out = (float*)d_out;

    // 16 groups per 256-thread block -> 262144/16 = 16384 blocks, exact
    afm_kernel<<<G_TOTAL / 16, 256, 0, stream>>>(
        group, embed, W1, b1, W2, b2, Wp, bp, out);
}

// Round 2
// 336.776 us; speedup vs baseline: 1.0005x; 1.0005x over previous
//
#include <hip/hip_runtime.h>
#include <math.h>

// afm_27805618274715 v2: 4 lanes per group (lane owns 16 of 64 dims),
// 16 groups per wave, 64 groups per 256-thread block.
// 12 independent float4 gather loads in flight per thread (ILP for the
// random-row gather); W1 + group indices staged in LDS.

static constexpr int G_TOTAL = 262144;
static constexpr int GPB = 64;   // groups per block

__device__ __forceinline__ float sigf(float x) {
    return 1.0f / (1.0f + expf(-x));
}

__global__ __launch_bounds__(256) void afm_kernel(
    const int*   __restrict__ group,   // [G,3]
    const float* __restrict__ embed,   // [1M,64]
    const float* __restrict__ W1,      // [64,4] row-major
    const float* __restrict__ b1,      // [4]
    const float* __restrict__ W2,      // [4]
    const float* __restrict__ b2,      // [1]
    const float* __restrict__ Wp,      // [3]
    const float* __restrict__ bp,      // [1]
    float*       __restrict__ out)     // [G]
{
    __shared__ int    s_idx[GPB * 3];   // 192 ints
    __shared__ float4 s_w1[64];         // W1: one float4 (4 features) per dim

    const int t = threadIdx.x;

    // cooperative staging: 192 coalesced index ints + 64 float4 of W1
    if (t < GPB * 3) s_idx[t] = group[blockIdx.x * (GPB * 3) + t];
    if (t < 64)      s_w1[t] = ((const float4*)W1)[t];
    __syncthreads();

    const int sub = t >> 2;          // group within block (0..63)
    const int l   = t & 3;           // lane within 4-lane subgroup
    const int g   = blockIdx.x * GPB + sub;

    const int i0 = s_idx[sub * 3 + 0];
    const int i1 = s_idx[sub * 3 + 1];
    const int i2 = s_idx[sub * 3 + 2];

    const float4* p0 = (const float4*)(embed + (size_t)i0 * 64);
    const float4* p1 = (const float4*)(embed + (size_t)i1 * 64);
    const float4* p2 = (const float4*)(embed + (size_t)i2 * 64);

    // 12 independent 16B loads; instruction j covers contiguous 64B per subgroup
    float4 e0[4], e1[4], e2[4];
#pragma unroll
    for (int j = 0; j < 4; ++j) {
        e0[j] = p0[j * 4 + l];
        e1[j] = p1[j * 4 + l];
        e2[j] = p2[j * 4 + l];
    }

    float4 acc01 = {0,0,0,0}, acc02 = {0,0,0,0}, acc12 = {0,0,0,0};
#pragma unroll
    for (int j = 0; j < 4; ++j) {
        const float4 a = e0[j], b = e1[j], c = e2[j];
        const float v01[4] = {a.x*b.x, a.y*b.y, a.z*b.z, a.w*b.w};
        const float v02[4] = {a.x*c.x, a.y*c.y, a.z*c.z, a.w*c.w};
        const float v12[4] = {b.x*c.x, b.y*c.y, b.z*c.z, b.w*c.w};
#pragma unroll
        for (int k = 0; k < 4; ++k) {
            const float4 w = s_w1[j * 16 + l * 4 + k];  // dim = 4*(4j+l)+k
            acc01.x = fmaf(v01[k], w.x, acc01.x);
            acc01.y = fmaf(v01[k], w.y, acc01.y);
            acc01.z = fmaf(v01[k], w.z, acc01.z);
            acc01.w = fmaf(v01[k], w.w, acc01.w);
            acc02.x = fmaf(v02[k], w.x, acc02.x);
            acc02.y = fmaf(v02[k], w.y, acc02.y);
            acc02.z = fmaf(v02[k], w.z, acc02.z);
            acc02.w = fmaf(v02[k], w.w, acc02.w);
            acc12.x = fmaf(v12[k], w.x, acc12.x);
            acc12.y = fmaf(v12[k], w.y, acc12.y);
            acc12.z = fmaf(v12[k], w.z, acc12.z);
            acc12.w = fmaf(v12[k], w.w, acc12.w);
        }
    }

    // reduce across the 4-lane subgroup (xor masks 2,1 stay in-subgroup)
#pragma unroll
    for (int m = 2; m >= 1; m >>= 1) {
        acc01.x += __shfl_xor(acc01.x, m);
        acc01.y += __shfl_xor(acc01.y, m);
        acc01.z += __shfl_xor(acc01.z, m);
        acc01.w += __shfl_xor(acc01.w, m);
        acc02.x += __shfl_xor(acc02.x, m);
        acc02.y += __shfl_xor(acc02.y, m);
        acc02.z += __shfl_xor(acc02.z, m);
        acc02.w += __shfl_xor(acc02.w, m);
        acc12.x += __shfl_xor(acc12.x, m);
        acc12.y += __shfl_xor(acc12.y, m);
        acc12.z += __shfl_xor(acc12.z, m);
        acc12.w += __shfl_xor(acc12.w, m);
    }

    // epilogue (redundant on 4 lanes; one wave-wide issue serves 16 groups)
    const float b10 = b1[0], b11 = b1[1], b12v = b1[2], b13 = b1[3];
    const float w20 = W2[0], w21 = W2[1], w22 = W2[2], w23 = W2[3];
    const float b2v = b2[0];

    const float a0 = b2v + sigf(acc01.x + b10) * w20 + sigf(acc01.y + b11) * w21
                         + sigf(acc01.z + b12v) * w22 + sigf(acc01.w + b13) * w23;
    const float a1 = b2v + sigf(acc02.x + b10) * w20 + sigf(acc02.y + b11) * w21
                         + sigf(acc02.z + b12v) * w22 + sigf(acc02.w + b13) * w23;
    const float a2 = b2v + sigf(acc12.x + b10) * w20 + sigf(acc12.y + b11) * w21
                         + sigf(acc12.z + b12v) * w22 + sigf(acc12.w + b13) * w23;

    const float z = bp[0] + a0 * Wp[0] + a1 * Wp[1] + a2 * Wp[2];
    const float res = 2.0f / (1.0f + expf(-z)) - 1.0f;

    if (l == 0) out[g] = res;
}

extern "C" void kernel_launch(void* const* d_in, const int* in_sizes, int n_in,
                              void* d_out, int out_size, void* d_ws, size_t ws_size,
                              hipStream_t stream) {
    const int*   group = (const int*)  d_in[0];
    const float* embed = (const float*)d_in[1];
    const float* W1    = (const float*)d_in[2];
    const float* b1    = (const float*)d_in[3];
    const float* W2    = (const float*)d_in[4];
    const float* b2    = (const float*)d_in[5];
    const float* Wp    = (const float*)d_in[6];
    const float* bp    = (const float*)d_in[7];
    float* out = (float*)d_out;

    afm_kernel<<<G_TOTAL / GPB, 256, 0, stream>>>(
        group, embed, W1, b1, W2, b2, Wp, bp, out);
}